// Round 16
// baseline (278.595 us; speedup 1.0000x reference)
//
#include <hip/hip_runtime.h>
#include <hip/hip_bf16.h>

// Problem constants
constexpr int N_  = 50000;
constexpr int E_  = 800000;
constexpr int ET_ = 850000;   // edges + self loops
constexpr float NEG_SLOPE = 0.2f;

constexpr int SCAN_NB = (N_ + 255) / 256;   // 196 scan blocks
constexpr int CSR_CAP = 1250008;            // sum ceil8(count) <= 850K+400K, +8 slack

typedef __attribute__((ext_vector_type(8))) short short8;   // 8 bf16 = 4 VGPRs
typedef __attribute__((ext_vector_type(4))) float f32x4;    // MFMA accumulator
typedef __attribute__((ext_vector_type(2))) float f32x2;    // packed fp32 pair

__device__ inline float leaky(float v) { return fmaxf(v, NEG_SLOPE * v); }

// bf16 round-to-nearest-even (matches __float2bfloat16)
__device__ inline unsigned bf16rn(float f) {
    union { float f; unsigned u; } v; v.f = f;
    return (v.u + 0x7fffu + ((v.u >> 16) & 1u)) >> 16;
}
__device__ inline f32x2 unpack2v(unsigned u) {
    f32x2 r;
    r.x = __uint_as_float(u << 16);
    r.y = __uint_as_float(u & 0xffff0000u);
    return r;
}

// ======================= CSR build (dst-sorted, 8-aligned segments) =======================
__global__ __launch_bounds__(256) void hist_kernel(
        const int* __restrict__ ei, int* __restrict__ count, int* __restrict__ off) {
    int e = blockIdx.x * 256 + threadIdx.x;
    if (e >= ET_) return;
    int d = (e < E_) ? ei[E_ + e] : e - E_;
    off[e] = atomicAdd(&count[d], 1);
}

// scan over ceil8(count): start[] offsets are 8-aligned per node
__global__ __launch_bounds__(256) void scan_partial(
        const int* __restrict__ count, int* __restrict__ bsum) {
    __shared__ int red[256];
    int t = threadIdx.x;
    int i = blockIdx.x * 256 + t;
    red[t] = (i < N_) ? ((count[i] + 7) & ~7) : 0;
    __syncthreads();
    #pragma unroll
    for (int o = 128; o > 0; o >>= 1) {
        if (t < o) red[t] += red[t + o];
        __syncthreads();
    }
    if (t == 0) bsum[blockIdx.x] = red[0];
}

__global__ __launch_bounds__(256) void scan_top(
        const int* __restrict__ bsum, int* __restrict__ bstart) {
    __shared__ int buf[256];
    int t = threadIdx.x;
    int v = (t < SCAN_NB) ? bsum[t] : 0;
    buf[t] = v;
    __syncthreads();
    #pragma unroll
    for (int o = 1; o < 256; o <<= 1) {
        int add = (t >= o) ? buf[t - o] : 0;
        __syncthreads();
        buf[t] += add;
        __syncthreads();
    }
    if (t < SCAN_NB) bstart[t] = buf[t] - v;   // exclusive
}

__global__ __launch_bounds__(256) void scan_final(
        const int* __restrict__ count, const int* __restrict__ bstart,
        int* __restrict__ start) {
    __shared__ int buf[256];
    int t = threadIdx.x;
    int i = blockIdx.x * 256 + t;
    int v = (i < N_) ? ((count[i] + 7) & ~7) : 0;
    buf[t] = v;
    __syncthreads();
    #pragma unroll
    for (int o = 1; o < 256; o <<= 1) {
        int add = (t >= o) ? buf[t - o] : 0;
        __syncthreads();
        buf[t] += add;
        __syncthreads();
    }
    if (i < N_) start[i] = bstart[blockIdx.x] + buf[t] - v;
}

__global__ __launch_bounds__(256) void scatter_kernel(
        const int* __restrict__ ei, const int* __restrict__ start,
        const int* __restrict__ off, int* __restrict__ csr_src) {
    int e = blockIdx.x * 256 + threadIdx.x;
    if (e >= ET_) return;
    int s, d;
    if (e < E_) { s = ei[e]; d = ei[E_ + e]; }
    else        { s = e - E_; d = s; }
    csr_src[start[d] + off[e]] = s;
}

// ============ W1 + W2 -> B-fragment-swizzled bf16 (one kernel) ============
__global__ __launch_bounds__(256) void convert_w_all(
        const float* __restrict__ W1l, const float* __restrict__ W1r,
        const float* __restrict__ W2l, const float* __restrict__ W2r,
        unsigned short* __restrict__ wsw, unsigned short* __restrict__ wsw2) {
    int tid = blockIdx.x * 256 + threadIdx.x;   // 0..49151
    if (tid >= 49152) return;
    if (tid < 32768) {
        int j    = tid & 7;
        int lane = (tid >> 3) & 63;
        int ks   = (tid >> 9) & 3;
        int ct   = tid >> 11;
        int k = ks * 32 + ((lane >> 4) & 3) * 8 + j;
        int c = ct * 16 + (lane & 15);
        float v = (c < 128) ? W1l[k * 128 + c] : W1r[k * 128 + (c - 128)];
        wsw[tid] = (unsigned short)bf16rn(v);
    } else {
        int t2   = tid - 32768;                 // 0..16383
        int j    = t2 & 7;
        int lane = (t2 >> 3) & 63;
        int ks   = (t2 >> 9) & 3;
        int ct   = t2 >> 11;                    // 0..7
        int k = ks * 32 + ((lane >> 4) & 3) * 8 + j;
        int c = ct * 16 + (lane & 15);
        float v = (c < 64) ? W2l[k * 64 + c] : W2r[k * 64 + (c - 64)];
        wsw2[t2] = (unsigned short)bf16rn(v);
    }
}

// ======================= layer 1 node transforms (MFMA) =======================
// (r13/r14-validated) Flat grid: 3125 blocks x 256. Wave: 16 rows x 4 col-tiles.
__global__ __launch_bounds__(256) void gemm1_mfma(
        const float* __restrict__ x,
        const unsigned short* __restrict__ wsw,
        const float* __restrict__ bl, const float* __restrict__ br,
        unsigned short* __restrict__ xlu, float* __restrict__ xr1) {
    const int wave = threadIdx.x >> 6;
    const int lane = threadIdx.x & 63;
    const int n0 = blockIdx.x * 16;
    const int m = lane & 15;
    const int q = (lane >> 4) & 3;
    const float* __restrict__ arow = x + (size_t)(n0 + m) * 128 + q * 8;
    short8 afrag[4];
    #pragma unroll
    for (int ks = 0; ks < 4; ++ks) {
        float4 v0 = *(const float4*)(arow + ks * 32);
        float4 v1 = *(const float4*)(arow + ks * 32 + 4);
        short8 a;
        a[0] = (short)bf16rn(v0.x); a[1] = (short)bf16rn(v0.y);
        a[2] = (short)bf16rn(v0.z); a[3] = (short)bf16rn(v0.w);
        a[4] = (short)bf16rn(v1.x); a[5] = (short)bf16rn(v1.y);
        a[6] = (short)bf16rn(v1.z); a[7] = (short)bf16rn(v1.w);
        afrag[ks] = a;
    }
    #pragma unroll
    for (int i = 0; i < 4; ++i) {
        const int ct = wave * 4 + i;
        f32x4 acc = {0.f, 0.f, 0.f, 0.f};
        #pragma unroll
        for (int ks = 0; ks < 4; ++ks) {
            short8 b = *(const short8*)(wsw + ((size_t)(ct * 4 + ks) * 64 + lane) * 8);
            acc = __builtin_amdgcn_mfma_f32_16x16x32_bf16(afrag[ks], b, acc, 0, 0, 0);
        }
        const int col = ct * 16 + m;
        if (ct < 8) {
            float bias = bl[col];
            #pragma unroll
            for (int j = 0; j < 4; ++j) {
                int row = n0 + q * 4 + j;
                xlu[(size_t)row * 128 + col] = (unsigned short)bf16rn(acc[j] + bias);
            }
        } else {
            float bias = br[col - 128];
            #pragma unroll
            for (int j = 0; j < 4; ++j) {
                int row = n0 + q * 4 + j;
                xr1[(size_t)row * 128 + (col - 128)] = acc[j] + bias;
            }
        }
    }
}

// ====== layer 1 fused attention: ONE wave per node, packed-f32 math ======
// Inner math on ext_vector f32x2 -> v_pk_{add,mul,max,fma}_f32 codegen.
// Arithmetic identical to r15 (IEEE fp32 pairs), only fewer issue slots.
__global__ __launch_bounds__(256) void fused1(
        const int* __restrict__ csr_src, const int* __restrict__ start,
        const int* __restrict__ count,
        const unsigned* __restrict__ xl1b, const float* __restrict__ xr1,
        const float* __restrict__ att, const float* __restrict__ bias1,
        float* __restrict__ hout) {
    int t = blockIdx.x * 256 + threadIdx.x;
    int n = __builtin_amdgcn_readfirstlane(t >> 6);   // wave-uniform node id
    int lane = t & 63;
    if (n >= N_) return;
    f32x2 xrv = *(const f32x2*)(xr1 + (size_t)n * 128 + 2 * lane);
    f32x2 avv = *(const f32x2*)(att + 2 * lane);
    int p0 = __builtin_amdgcn_readfirstlane(start[n]);
    int p1 = p0 + __builtin_amdgcn_readfirstlane(count[n]);
    f32x2 accv = {0.f, 0.f};
    float l = 0.f;
    for (int p = p0; p < p1; p += 4) {
        int4 si = *(const int4*)(csr_src + p);         // uniform, 16B-aligned
        int s0 = __builtin_amdgcn_readfirstlane(si.x);
        int s1 = __builtin_amdgcn_readfirstlane(si.y);
        int s2 = __builtin_amdgcn_readfirstlane(si.z);
        int s3 = __builtin_amdgcn_readfirstlane(si.w);
        f32x2 x0 = unpack2v(xl1b[(size_t)s0 * 64 + lane]);
        f32x2 x1 = unpack2v(xl1b[(size_t)s1 * 64 + lane]);
        f32x2 x2 = unpack2v(xl1b[(size_t)s2 * 64 + lane]);
        f32x2 x3 = unpack2v(xl1b[(size_t)s3 * 64 + lane]);
        f32x2 m0 = x0 + xrv, m1 = x1 + xrv, m2 = x2 + xrv, m3 = x3 + xrv;
        f32x2 k0 = __builtin_elementwise_max(m0, m0 * NEG_SLOPE) * avv;
        f32x2 k1 = __builtin_elementwise_max(m1, m1 * NEG_SLOPE) * avv;
        f32x2 k2 = __builtin_elementwise_max(m2, m2 * NEG_SLOPE) * avv;
        f32x2 k3 = __builtin_elementwise_max(m3, m3 * NEG_SLOPE) * avv;
        float a0 = k0.x + k0.y;
        float a1 = k1.x + k1.y;
        float a2 = k2.x + k2.y;
        float a3 = k3.x + k3.y;
        a0 += __shfl_xor(a0, 1); a1 += __shfl_xor(a1, 1);
        a2 += __shfl_xor(a2, 1); a3 += __shfl_xor(a3, 1);
        a0 += __shfl_xor(a0, 2); a1 += __shfl_xor(a1, 2);
        a2 += __shfl_xor(a2, 2); a3 += __shfl_xor(a3, 2);
        a0 += __shfl_xor(a0, 4); a1 += __shfl_xor(a1, 4);
        a2 += __shfl_xor(a2, 4); a3 += __shfl_xor(a3, 4);
        float w0 = __expf(a0);
        float w1 = p + 1 < p1 ? __expf(a1) : 0.f;
        float w2 = p + 2 < p1 ? __expf(a2) : 0.f;
        float w3 = p + 3 < p1 ? __expf(a3) : 0.f;
        accv = __builtin_elementwise_fma(x0, (f32x2){w0, w0}, accv); l += w0;
        accv = __builtin_elementwise_fma(x1, (f32x2){w1, w1}, accv); l += w1;
        accv = __builtin_elementwise_fma(x2, (f32x2){w2, w2}, accv); l += w2;
        accv = __builtin_elementwise_fma(x3, (f32x2){w3, w3}, accv); l += w3;
    }
    f32x2 bv = *(const f32x2*)(bias1 + 2 * lane);
    float vx = accv.x / l + bv.x;
    float vy = accv.y / l + bv.y;
    float2 o;
    o.x = vx > 0.f ? vx : (__expf(vx) - 1.f);
    o.y = vy > 0.f ? vy : (__expf(vy) - 1.f);
    *(float2*)(hout + (size_t)n * 128 + 2 * lane) = o;
}

// ======================= layer 2 node transforms (MFMA) =======================
// (r14-validated) 8 col-tiles (ct<4 -> xl2b bf16, else xr2 f32); 2 tiles/wave.
__global__ __launch_bounds__(256) void gemm2_mfma(
        const float* __restrict__ hbuf,
        const unsigned short* __restrict__ wsw2,
        const float* __restrict__ bl, const float* __restrict__ br,
        unsigned short* __restrict__ xlu2, float* __restrict__ xr2) {
    const int wave = threadIdx.x >> 6;
    const int lane = threadIdx.x & 63;
    const int n0 = blockIdx.x * 16;
    const int m = lane & 15;
    const int q = (lane >> 4) & 3;
    const float* __restrict__ arow = hbuf + (size_t)(n0 + m) * 128 + q * 8;
    short8 afrag[4];
    #pragma unroll
    for (int ks = 0; ks < 4; ++ks) {
        float4 v0 = *(const float4*)(arow + ks * 32);
        float4 v1 = *(const float4*)(arow + ks * 32 + 4);
        short8 a;
        a[0] = (short)bf16rn(v0.x); a[1] = (short)bf16rn(v0.y);
        a[2] = (short)bf16rn(v0.z); a[3] = (short)bf16rn(v0.w);
        a[4] = (short)bf16rn(v1.x); a[5] = (short)bf16rn(v1.y);
        a[6] = (short)bf16rn(v1.z); a[7] = (short)bf16rn(v1.w);
        afrag[ks] = a;
    }
    #pragma unroll
    for (int i = 0; i < 2; ++i) {
        const int ct = wave * 2 + i;
        f32x4 acc = {0.f, 0.f, 0.f, 0.f};
        #pragma unroll
        for (int ks = 0; ks < 4; ++ks) {
            short8 b = *(const short8*)(wsw2 + ((size_t)(ct * 4 + ks) * 64 + lane) * 8);
            acc = __builtin_amdgcn_mfma_f32_16x16x32_bf16(afrag[ks], b, acc, 0, 0, 0);
        }
        const int col = ct * 16 + m;
        if (ct < 4) {
            float bias = bl[col];
            #pragma unroll
            for (int j = 0; j < 4; ++j) {
                int row = n0 + q * 4 + j;
                xlu2[(size_t)row * 64 + col] = (unsigned short)bf16rn(acc[j] + bias);
            }
        } else {
            float bias = br[col - 64];
            #pragma unroll
            for (int j = 0; j < 4; ++j) {
                int row = n0 + q * 4 + j;
                xr2[(size_t)row * 64 + (col - 64)] = acc[j] + bias;
            }
        }
    }
}

// ====== layer 2 fused attention: one wave per node, packed-f32 math ======
__global__ __launch_bounds__(256) void fused2(
        const int* __restrict__ csr_src, const int* __restrict__ start,
        const int* __restrict__ count,
        const unsigned* __restrict__ xl2b, const float* __restrict__ xr2,
        const float* __restrict__ att, const float* __restrict__ bias2,
        float* __restrict__ out) {
    int t = blockIdx.x * 256 + threadIdx.x;
    int n = __builtin_amdgcn_readfirstlane(t >> 6);   // wave-uniform node id
    int lane = t & 63;
    int half = lane >> 5;                 // which edge of the pair
    int lc   = lane & 31;                 // channel pair id
    if (n >= N_) return;
    f32x2 xrv = *(const f32x2*)(xr2 + (size_t)n * 64 + 2 * lc);
    f32x2 avv = *(const f32x2*)(att + 2 * lc);
    int p0 = __builtin_amdgcn_readfirstlane(start[n]);
    int p1 = p0 + __builtin_amdgcn_readfirstlane(count[n]);
    f32x2 accv = {0.f, 0.f};
    float l = 0.f;
    for (int p = p0; p < p1; p += 8) {
        int4 ia = *(const int4*)(csr_src + p);         // uniform, aligned
        int4 ib = *(const int4*)(csr_src + p + 4);
        int sx[8];
        sx[0] = __builtin_amdgcn_readfirstlane(ia.x);
        sx[1] = __builtin_amdgcn_readfirstlane(ia.y);
        sx[2] = __builtin_amdgcn_readfirstlane(ia.z);
        sx[3] = __builtin_amdgcn_readfirstlane(ia.w);
        sx[4] = __builtin_amdgcn_readfirstlane(ib.x);
        sx[5] = __builtin_amdgcn_readfirstlane(ib.y);
        sx[6] = __builtin_amdgcn_readfirstlane(ib.z);
        sx[7] = __builtin_amdgcn_readfirstlane(ib.w);
        #pragma unroll
        for (int u = 0; u < 4; ++u) {
            int pe = p + 2 * u + half;
            int s  = sx[2 * u + half];
            f32x2 xv = unpack2v(xl2b[(size_t)s * 32 + lc]);
            f32x2 m = xv + xrv;
            f32x2 k = __builtin_elementwise_max(m, m * NEG_SLOPE) * avv;
            float a = k.x + k.y;
            a += __shfl_xor(a, 1);
            a += __shfl_xor(a, 2);
            a += __shfl_xor(a, 4);
            a += __shfl_xor(a, 8);
            a += __shfl_xor(a, 16);
            float w = pe < p1 ? __expf(a) : 0.f;
            accv = __builtin_elementwise_fma(xv, (f32x2){w, w}, accv);
            l += w;
        }
    }
    accv.x += __shfl_xor(accv.x, 32);
    accv.y += __shfl_xor(accv.y, 32);
    l      += __shfl_xor(l, 32);
    if (half == 0) {
        f32x2 bv = *(const f32x2*)(bias2 + 2 * lc);
        float2 o;
        o.x = accv.x / l + bv.x;
        o.y = accv.y / l + bv.y;
        *(float2*)(out + (size_t)n * 64 + 2 * lc) = o;
    }
}

extern "C" void kernel_launch(void* const* d_in, const int* in_sizes, int n_in,
                              void* d_out, int out_size, void* d_ws, size_t ws_size,
                              hipStream_t stream) {
    (void)in_sizes; (void)n_in; (void)out_size; (void)ws_size;
    const float* x     = (const float*)d_in[0];
    const int*   ei    = (const int*)d_in[1];
    const float* W1l   = (const float*)d_in[2];
    const float* b1l   = (const float*)d_in[3];
    const float* W1r   = (const float*)d_in[4];
    const float* b1r   = (const float*)d_in[5];
    const float* att1  = (const float*)d_in[6];
    const float* bias1 = (const float*)d_in[7];
    const float* W2l   = (const float*)d_in[8];
    const float* b2l   = (const float*)d_in[9];
    const float* W2r   = (const float*)d_in[10];
    const float* b2r   = (const float*)d_in[11];
    const float* att2  = (const float*)d_in[12];
    const float* bias2 = (const float*)d_in[13];
    float* out = (float*)d_out;

    // workspace layout (r15-identical). count+csr_src contiguous: ONE memset
    // zeroes both (csr pad slots must be 0 every call).
    float* xr1      = (float*)d_ws;                // 6,400,000 f
    float* hbuf     = xr1 + 6400000;               // 6,400,000 f
    unsigned* xl1b  = (unsigned*)(hbuf + 6400000); // 3,200,000 u (bf16 pairs)
    int* count   = (int*)(xl1b + 3200000);         //    50,000 i
    int* csr_src = count + 50000;                  // 1,250,008 i (8-aligned segs)
    int* startp  = csr_src + CSR_CAP;              //    50,000 i
    int* off     = startp + 50000;                 //   850,000 i
    int* bsum    = off + 850000;                   //       256 i
    int* bstart  = bsum + 256;                     //       256 i
    unsigned short* wsw2 = (unsigned short*)(bstart + 256);  // 16,384 bf16 (32 KB)
    unsigned* xl2b = xl1b;                         // alias: xl1b dead after fused1
    float* xr2     = xr1;                          // alias: xr1 dead after fused1
    unsigned short* wsw = (unsigned short*)hbuf;   // 64 KB W1 frags in hbuf front

    hipMemsetAsync((void*)count, 0, (size_t)(50000 + CSR_CAP) * 4, stream);

    const int EB = (ET_ + 255) / 256;
    hist_kernel <<<EB, 256, 0, stream>>>(ei, count, off);
    scan_partial<<<SCAN_NB, 256, 0, stream>>>(count, bsum);
    scan_top    <<<1, 256, 0, stream>>>(bsum, bstart);
    scan_final  <<<SCAN_NB, 256, 0, stream>>>(count, bstart, startp);
    scatter_kernel<<<EB, 256, 0, stream>>>(ei, startp, off, csr_src);

    convert_w_all<<<192, 256, 0, stream>>>(W1l, W1r, W2l, W2r, wsw, wsw2);
    gemm1_mfma <<<N_ / 16, 256, 0, stream>>>(x, wsw, b1l, b1r,
                                             (unsigned short*)xl1b, xr1);
    fused1<<<(N_ * 64 + 255) / 256, 256, 0, stream>>>(csr_src, startp, count,
                                                      xl1b, xr1, att1, bias1, hbuf);

    gemm2_mfma <<<N_ / 16, 256, 0, stream>>>(hbuf, wsw2, b2l, b2r,
                                             (unsigned short*)xl2b, xr2);
    fused2<<<(N_ * 64 + 255) / 256, 256, 0, stream>>>(csr_src, startp, count,
                                                      xl2b, xr2, att2, bias2, out);
}

// Round 17
// 275.849 us; speedup vs baseline: 1.0100x; 1.0100x over previous
//
#include <hip/hip_runtime.h>
#include <hip/hip_bf16.h>

// Problem constants
constexpr int N_  = 50000;
constexpr int E_  = 800000;
constexpr int ET_ = 850000;   // edges + self loops
constexpr float NEG_SLOPE = 0.2f;

constexpr int SCAN_NB = (N_ + 255) / 256;   // 196 scan blocks
constexpr int CSR_CAP = 1250008;            // sum ceil8(count) <= 850K+400K, +8 slack

typedef __attribute__((ext_vector_type(8))) short short8;   // 8 bf16 = 4 VGPRs
typedef __attribute__((ext_vector_type(4))) float f32x4;    // MFMA accumulator

__device__ inline float leaky(float v) { return fmaxf(v, NEG_SLOPE * v); }

// bf16 round-to-nearest-even (matches __float2bfloat16)
__device__ inline unsigned bf16rn(float f) {
    union { float f; unsigned u; } v; v.f = f;
    return (v.u + 0x7fffu + ((v.u >> 16) & 1u)) >> 16;
}
__device__ inline float2 unpack2(unsigned u) {
    return make_float2(__uint_as_float(u << 16), __uint_as_float(u & 0xffff0000u));
}

// ======================= CSR build (dst-sorted, 8-aligned segments) =======================
__global__ __launch_bounds__(256) void hist_kernel(
        const int* __restrict__ ei, int* __restrict__ count, int* __restrict__ off) {
    int e = blockIdx.x * 256 + threadIdx.x;
    if (e >= ET_) return;
    int d = (e < E_) ? ei[E_ + e] : e - E_;
    off[e] = atomicAdd(&count[d], 1);
}

// scan over ceil8(count): start[] offsets are 8-aligned per node
__global__ __launch_bounds__(256) void scan_partial(
        const int* __restrict__ count, int* __restrict__ bsum) {
    __shared__ int red[256];
    int t = threadIdx.x;
    int i = blockIdx.x * 256 + t;
    red[t] = (i < N_) ? ((count[i] + 7) & ~7) : 0;
    __syncthreads();
    #pragma unroll
    for (int o = 128; o > 0; o >>= 1) {
        if (t < o) red[t] += red[t + o];
        __syncthreads();
    }
    if (t == 0) bsum[blockIdx.x] = red[0];
}

__global__ __launch_bounds__(256) void scan_top(
        const int* __restrict__ bsum, int* __restrict__ bstart) {
    __shared__ int buf[256];
    int t = threadIdx.x;
    int v = (t < SCAN_NB) ? bsum[t] : 0;
    buf[t] = v;
    __syncthreads();
    #pragma unroll
    for (int o = 1; o < 256; o <<= 1) {
        int add = (t >= o) ? buf[t - o] : 0;
        __syncthreads();
        buf[t] += add;
        __syncthreads();
    }
    if (t < SCAN_NB) bstart[t] = buf[t] - v;   // exclusive
}

__global__ __launch_bounds__(256) void scan_final(
        const int* __restrict__ count, const int* __restrict__ bstart,
        int* __restrict__ start) {
    __shared__ int buf[256];
    int t = threadIdx.x;
    int i = blockIdx.x * 256 + t;
    int v = (i < N_) ? ((count[i] + 7) & ~7) : 0;
    buf[t] = v;
    __syncthreads();
    #pragma unroll
    for (int o = 1; o < 256; o <<= 1) {
        int add = (t >= o) ? buf[t - o] : 0;
        __syncthreads();
        buf[t] += add;
        __syncthreads();
    }
    if (i < N_) start[i] = bstart[blockIdx.x] + buf[t] - v;
}

__global__ __launch_bounds__(256) void scatter_kernel(
        const int* __restrict__ ei, const int* __restrict__ start,
        const int* __restrict__ off, int* __restrict__ csr_src) {
    int e = blockIdx.x * 256 + threadIdx.x;
    if (e >= ET_) return;
    int s, d;
    if (e < E_) { s = ei[e]; d = ei[E_ + e]; }
    else        { s = e - E_; d = s; }
    csr_src[start[d] + off[e]] = s;
}

// ============ W1 + W2 -> B-fragment-swizzled bf16 (one kernel) ============
__global__ __launch_bounds__(256) void convert_w_all(
        const float* __restrict__ W1l, const float* __restrict__ W1r,
        const float* __restrict__ W2l, const float* __restrict__ W2r,
        unsigned short* __restrict__ wsw, unsigned short* __restrict__ wsw2) {
    int tid = blockIdx.x * 256 + threadIdx.x;   // 0..49151
    if (tid >= 49152) return;
    if (tid < 32768) {
        int j    = tid & 7;
        int lane = (tid >> 3) & 63;
        int ks   = (tid >> 9) & 3;
        int ct   = tid >> 11;
        int k = ks * 32 + ((lane >> 4) & 3) * 8 + j;
        int c = ct * 16 + (lane & 15);
        float v = (c < 128) ? W1l[k * 128 + c] : W1r[k * 128 + (c - 128)];
        wsw[tid] = (unsigned short)bf16rn(v);
    } else {
        int t2   = tid - 32768;                 // 0..16383
        int j    = t2 & 7;
        int lane = (t2 >> 3) & 63;
        int ks   = (t2 >> 9) & 3;
        int ct   = t2 >> 11;                    // 0..7
        int k = ks * 32 + ((lane >> 4) & 3) * 8 + j;
        int c = ct * 16 + (lane & 15);
        float v = (c < 64) ? W2l[k * 64 + c] : W2r[k * 64 + (c - 64)];
        wsw2[t2] = (unsigned short)bf16rn(v);
    }
}

// ======================= layer 1 node transforms (MFMA) =======================
// (r13/r14-validated) Flat grid: 3125 blocks x 256. Wave: 16 rows x 4 col-tiles.
__global__ __launch_bounds__(256) void gemm1_mfma(
        const float* __restrict__ x,
        const unsigned short* __restrict__ wsw,
        const float* __restrict__ bl, const float* __restrict__ br,
        unsigned short* __restrict__ xlu, float* __restrict__ xr1) {
    const int wave = threadIdx.x >> 6;
    const int lane = threadIdx.x & 63;
    const int n0 = blockIdx.x * 16;
    const int m = lane & 15;
    const int q = (lane >> 4) & 3;
    const float* __restrict__ arow = x + (size_t)(n0 + m) * 128 + q * 8;
    short8 afrag[4];
    #pragma unroll
    for (int ks = 0; ks < 4; ++ks) {
        float4 v0 = *(const float4*)(arow + ks * 32);
        float4 v1 = *(const float4*)(arow + ks * 32 + 4);
        short8 a;
        a[0] = (short)bf16rn(v0.x); a[1] = (short)bf16rn(v0.y);
        a[2] = (short)bf16rn(v0.z); a[3] = (short)bf16rn(v0.w);
        a[4] = (short)bf16rn(v1.x); a[5] = (short)bf16rn(v1.y);
        a[6] = (short)bf16rn(v1.z); a[7] = (short)bf16rn(v1.w);
        afrag[ks] = a;
    }
    #pragma unroll
    for (int i = 0; i < 4; ++i) {
        const int ct = wave * 4 + i;
        f32x4 acc = {0.f, 0.f, 0.f, 0.f};
        #pragma unroll
        for (int ks = 0; ks < 4; ++ks) {
            short8 b = *(const short8*)(wsw + ((size_t)(ct * 4 + ks) * 64 + lane) * 8);
            acc = __builtin_amdgcn_mfma_f32_16x16x32_bf16(afrag[ks], b, acc, 0, 0, 0);
        }
        const int col = ct * 16 + m;
        if (ct < 8) {
            float bias = bl[col];
            #pragma unroll
            for (int j = 0; j < 4; ++j) {
                int row = n0 + q * 4 + j;
                xlu[(size_t)row * 128 + col] = (unsigned short)bf16rn(acc[j] + bias);
            }
        } else {
            float bias = br[col - 128];
            #pragma unroll
            for (int j = 0; j < 4; ++j) {
                int row = n0 + q * 4 + j;
                xr1[(size_t)row * 128 + (col - 128)] = acc[j] + bias;
            }
        }
    }
}

// ====== layer 1 fused attention: ONE wave per node, 8 edges in flight ======
// 8-aligned zero-padded CSR: two uniform int4 index loads, EIGHT independent
// gathers issued before any dependent math (2x MLP vs r15/r16). Tail edges
// masked by w=0 (pad slots gather node 0 harmlessly).
__global__ __launch_bounds__(256) void fused1(
        const int* __restrict__ csr_src, const int* __restrict__ start,
        const int* __restrict__ count,
        const unsigned* __restrict__ xl1b, const float* __restrict__ xr1,
        const float* __restrict__ att, const float* __restrict__ bias1,
        float* __restrict__ hout) {
    int t = blockIdx.x * 256 + threadIdx.x;
    int n = __builtin_amdgcn_readfirstlane(t >> 6);   // wave-uniform node id
    int lane = t & 63;
    if (n >= N_) return;
    float2 xr = *(const float2*)(xr1 + (size_t)n * 128 + 2 * lane);
    float2 av = *(const float2*)(att + 2 * lane);
    int p0 = __builtin_amdgcn_readfirstlane(start[n]);
    int p1 = p0 + __builtin_amdgcn_readfirstlane(count[n]);
    float2 acc = make_float2(0.f, 0.f);
    float l = 0.f;
    for (int p = p0; p < p1; p += 8) {
        int4 ia = *(const int4*)(csr_src + p);         // uniform, 16B-aligned
        int4 ib = *(const int4*)(csr_src + p + 4);
        int s0 = __builtin_amdgcn_readfirstlane(ia.x);
        int s1 = __builtin_amdgcn_readfirstlane(ia.y);
        int s2 = __builtin_amdgcn_readfirstlane(ia.z);
        int s3 = __builtin_amdgcn_readfirstlane(ia.w);
        int s4 = __builtin_amdgcn_readfirstlane(ib.x);
        int s5 = __builtin_amdgcn_readfirstlane(ib.y);
        int s6 = __builtin_amdgcn_readfirstlane(ib.z);
        int s7 = __builtin_amdgcn_readfirstlane(ib.w);
        float2 x0 = unpack2(xl1b[(size_t)s0 * 64 + lane]);
        float2 x1 = unpack2(xl1b[(size_t)s1 * 64 + lane]);
        float2 x2 = unpack2(xl1b[(size_t)s2 * 64 + lane]);
        float2 x3 = unpack2(xl1b[(size_t)s3 * 64 + lane]);
        float2 x4 = unpack2(xl1b[(size_t)s4 * 64 + lane]);
        float2 x5 = unpack2(xl1b[(size_t)s5 * 64 + lane]);
        float2 x6 = unpack2(xl1b[(size_t)s6 * 64 + lane]);
        float2 x7 = unpack2(xl1b[(size_t)s7 * 64 + lane]);
        float a0 = fmaf(leaky(x0.x + xr.x), av.x, leaky(x0.y + xr.y) * av.y);
        float a1 = fmaf(leaky(x1.x + xr.x), av.x, leaky(x1.y + xr.y) * av.y);
        float a2 = fmaf(leaky(x2.x + xr.x), av.x, leaky(x2.y + xr.y) * av.y);
        float a3 = fmaf(leaky(x3.x + xr.x), av.x, leaky(x3.y + xr.y) * av.y);
        float a4 = fmaf(leaky(x4.x + xr.x), av.x, leaky(x4.y + xr.y) * av.y);
        float a5 = fmaf(leaky(x5.x + xr.x), av.x, leaky(x5.y + xr.y) * av.y);
        float a6 = fmaf(leaky(x6.x + xr.x), av.x, leaky(x6.y + xr.y) * av.y);
        float a7 = fmaf(leaky(x7.x + xr.x), av.x, leaky(x7.y + xr.y) * av.y);
        a0 += __shfl_xor(a0, 1); a1 += __shfl_xor(a1, 1);
        a2 += __shfl_xor(a2, 1); a3 += __shfl_xor(a3, 1);
        a4 += __shfl_xor(a4, 1); a5 += __shfl_xor(a5, 1);
        a6 += __shfl_xor(a6, 1); a7 += __shfl_xor(a7, 1);
        a0 += __shfl_xor(a0, 2); a1 += __shfl_xor(a1, 2);
        a2 += __shfl_xor(a2, 2); a3 += __shfl_xor(a3, 2);
        a4 += __shfl_xor(a4, 2); a5 += __shfl_xor(a5, 2);
        a6 += __shfl_xor(a6, 2); a7 += __shfl_xor(a7, 2);
        a0 += __shfl_xor(a0, 4); a1 += __shfl_xor(a1, 4);
        a2 += __shfl_xor(a2, 4); a3 += __shfl_xor(a3, 4);
        a4 += __shfl_xor(a4, 4); a5 += __shfl_xor(a5, 4);
        a6 += __shfl_xor(a6, 4); a7 += __shfl_xor(a7, 4);
        float w0 = __expf(a0);
        float w1 = p + 1 < p1 ? __expf(a1) : 0.f;
        float w2 = p + 2 < p1 ? __expf(a2) : 0.f;
        float w3 = p + 3 < p1 ? __expf(a3) : 0.f;
        float w4 = p + 4 < p1 ? __expf(a4) : 0.f;
        float w5 = p + 5 < p1 ? __expf(a5) : 0.f;
        float w6 = p + 6 < p1 ? __expf(a6) : 0.f;
        float w7 = p + 7 < p1 ? __expf(a7) : 0.f;
        acc.x = fmaf(w0, x0.x, acc.x); acc.y = fmaf(w0, x0.y, acc.y); l += w0;
        acc.x = fmaf(w1, x1.x, acc.x); acc.y = fmaf(w1, x1.y, acc.y); l += w1;
        acc.x = fmaf(w2, x2.x, acc.x); acc.y = fmaf(w2, x2.y, acc.y); l += w2;
        acc.x = fmaf(w3, x3.x, acc.x); acc.y = fmaf(w3, x3.y, acc.y); l += w3;
        acc.x = fmaf(w4, x4.x, acc.x); acc.y = fmaf(w4, x4.y, acc.y); l += w4;
        acc.x = fmaf(w5, x5.x, acc.x); acc.y = fmaf(w5, x5.y, acc.y); l += w5;
        acc.x = fmaf(w6, x6.x, acc.x); acc.y = fmaf(w6, x6.y, acc.y); l += w6;
        acc.x = fmaf(w7, x7.x, acc.x); acc.y = fmaf(w7, x7.y, acc.y); l += w7;
    }
    float2 bv = *(const float2*)(bias1 + 2 * lane);
    float vx = acc.x / l + bv.x;
    float vy = acc.y / l + bv.y;
    float2 o;
    o.x = vx > 0.f ? vx : (__expf(vx) - 1.f);
    o.y = vy > 0.f ? vy : (__expf(vy) - 1.f);
    *(float2*)(hout + (size_t)n * 128 + 2 * lane) = o;
}

// ======================= layer 2 node transforms (MFMA) =======================
// (r14-validated) 8 col-tiles (ct<4 -> xl2b bf16, else xr2 f32); 2 tiles/wave.
__global__ __launch_bounds__(256) void gemm2_mfma(
        const float* __restrict__ hbuf,
        const unsigned short* __restrict__ wsw2,
        const float* __restrict__ bl, const float* __restrict__ br,
        unsigned short* __restrict__ xlu2, float* __restrict__ xr2) {
    const int wave = threadIdx.x >> 6;
    const int lane = threadIdx.x & 63;
    const int n0 = blockIdx.x * 16;
    const int m = lane & 15;
    const int q = (lane >> 4) & 3;
    const float* __restrict__ arow = hbuf + (size_t)(n0 + m) * 128 + q * 8;
    short8 afrag[4];
    #pragma unroll
    for (int ks = 0; ks < 4; ++ks) {
        float4 v0 = *(const float4*)(arow + ks * 32);
        float4 v1 = *(const float4*)(arow + ks * 32 + 4);
        short8 a;
        a[0] = (short)bf16rn(v0.x); a[1] = (short)bf16rn(v0.y);
        a[2] = (short)bf16rn(v0.z); a[3] = (short)bf16rn(v0.w);
        a[4] = (short)bf16rn(v1.x); a[5] = (short)bf16rn(v1.y);
        a[6] = (short)bf16rn(v1.z); a[7] = (short)bf16rn(v1.w);
        afrag[ks] = a;
    }
    #pragma unroll
    for (int i = 0; i < 2; ++i) {
        const int ct = wave * 2 + i;
        f32x4 acc = {0.f, 0.f, 0.f, 0.f};
        #pragma unroll
        for (int ks = 0; ks < 4; ++ks) {
            short8 b = *(const short8*)(wsw2 + ((size_t)(ct * 4 + ks) * 64 + lane) * 8);
            acc = __builtin_amdgcn_mfma_f32_16x16x32_bf16(afrag[ks], b, acc, 0, 0, 0);
        }
        const int col = ct * 16 + m;
        if (ct < 4) {
            float bias = bl[col];
            #pragma unroll
            for (int j = 0; j < 4; ++j) {
                int row = n0 + q * 4 + j;
                xlu2[(size_t)row * 64 + col] = (unsigned short)bf16rn(acc[j] + bias);
            }
        } else {
            float bias = br[col - 64];
            #pragma unroll
            for (int j = 0; j < 4; ++j) {
                int row = n0 + q * 4 + j;
                xr2[(size_t)row * 64 + (col - 64)] = acc[j] + bias;
            }
        }
    }
}

// ====== layer 2 fused attention: one wave per node, TWO edges at a time ======
// (r15-validated scalar form)
__global__ __launch_bounds__(256) void fused2(
        const int* __restrict__ csr_src, const int* __restrict__ start,
        const int* __restrict__ count,
        const unsigned* __restrict__ xl2b, const float* __restrict__ xr2,
        const float* __restrict__ att, const float* __restrict__ bias2,
        float* __restrict__ out) {
    int t = blockIdx.x * 256 + threadIdx.x;
    int n = __builtin_amdgcn_readfirstlane(t >> 6);   // wave-uniform node id
    int lane = t & 63;
    int half = lane >> 5;                 // which edge of the pair
    int lc   = lane & 31;                 // channel pair id
    if (n >= N_) return;
    float2 xr = *(const float2*)(xr2 + (size_t)n * 64 + 2 * lc);
    float2 av = *(const float2*)(att + 2 * lc);
    int p0 = __builtin_amdgcn_readfirstlane(start[n]);
    int p1 = p0 + __builtin_amdgcn_readfirstlane(count[n]);
    float2 acc = make_float2(0.f, 0.f);
    float l = 0.f;
    for (int p = p0; p < p1; p += 8) {
        int4 ia = *(const int4*)(csr_src + p);         // uniform, aligned
        int4 ib = *(const int4*)(csr_src + p + 4);
        int sx[8];
        sx[0] = __builtin_amdgcn_readfirstlane(ia.x);
        sx[1] = __builtin_amdgcn_readfirstlane(ia.y);
        sx[2] = __builtin_amdgcn_readfirstlane(ia.z);
        sx[3] = __builtin_amdgcn_readfirstlane(ia.w);
        sx[4] = __builtin_amdgcn_readfirstlane(ib.x);
        sx[5] = __builtin_amdgcn_readfirstlane(ib.y);
        sx[6] = __builtin_amdgcn_readfirstlane(ib.z);
        sx[7] = __builtin_amdgcn_readfirstlane(ib.w);
        #pragma unroll
        for (int u = 0; u < 4; ++u) {
            int pe = p + 2 * u + half;
            int s  = sx[2 * u + half];
            float2 xv = unpack2(xl2b[(size_t)s * 32 + lc]);
            float a = fmaf(leaky(xv.x + xr.x), av.x, leaky(xv.y + xr.y) * av.y);
            a += __shfl_xor(a, 1);
            a += __shfl_xor(a, 2);
            a += __shfl_xor(a, 4);
            a += __shfl_xor(a, 8);
            a += __shfl_xor(a, 16);
            float w = pe < p1 ? __expf(a) : 0.f;
            acc.x = fmaf(w, xv.x, acc.x);
            acc.y = fmaf(w, xv.y, acc.y);
            l += w;
        }
    }
    acc.x += __shfl_xor(acc.x, 32);
    acc.y += __shfl_xor(acc.y, 32);
    l     += __shfl_xor(l, 32);
    if (half == 0) {
        float2 bv = *(const float2*)(bias2 + 2 * lc);
        float2 o;
        o.x = acc.x / l + bv.x;
        o.y = acc.y / l + bv.y;
        *(float2*)(out + (size_t)n * 64 + 2 * lc) = o;
    }
}

extern "C" void kernel_launch(void* const* d_in, const int* in_sizes, int n_in,
                              void* d_out, int out_size, void* d_ws, size_t ws_size,
                              hipStream_t stream) {
    (void)in_sizes; (void)n_in; (void)out_size; (void)ws_size;
    const float* x     = (const float*)d_in[0];
    const int*   ei    = (const int*)d_in[1];
    const float* W1l   = (const float*)d_in[2];
    const float* b1l   = (const float*)d_in[3];
    const float* W1r   = (const float*)d_in[4];
    const float* b1r   = (const float*)d_in[5];
    const float* att1  = (const float*)d_in[6];
    const float* bias1 = (const float*)d_in[7];
    const float* W2l   = (const float*)d_in[8];
    const float* b2l   = (const float*)d_in[9];
    const float* W2r   = (const float*)d_in[10];
    const float* b2r   = (const float*)d_in[11];
    const float* att2  = (const float*)d_in[12];
    const float* bias2 = (const float*)d_in[13];
    float* out = (float*)d_out;

    // workspace layout (r15-identical). count+csr_src contiguous: ONE memset
    // zeroes both (csr pad slots must be 0 every call).
    float* xr1      = (float*)d_ws;                // 6,400,000 f
    float* hbuf     = xr1 + 6400000;               // 6,400,000 f
    unsigned* xl1b  = (unsigned*)(hbuf + 6400000); // 3,200,000 u (bf16 pairs)
    int* count   = (int*)(xl1b + 3200000);         //    50,000 i
    int* csr_src = count + 50000;                  // 1,250,008 i (8-aligned segs)
    int* startp  = csr_src + CSR_CAP;              //    50,000 i
    int* off     = startp + 50000;                 //   850,000 i
    int* bsum    = off + 850000;                   //       256 i
    int* bstart  = bsum + 256;                     //       256 i
    unsigned short* wsw2 = (unsigned short*)(bstart + 256);  // 16,384 bf16 (32 KB)
    unsigned* xl2b = xl1b;                         // alias: xl1b dead after fused1
    float* xr2     = xr1;                          // alias: xr1 dead after fused1
    unsigned short* wsw = (unsigned short*)hbuf;   // 64 KB W1 frags in hbuf front

    hipMemsetAsync((void*)count, 0, (size_t)(50000 + CSR_CAP) * 4, stream);

    const int EB = (ET_ + 255) / 256;
    hist_kernel <<<EB, 256, 0, stream>>>(ei, count, off);
    scan_partial<<<SCAN_NB, 256, 0, stream>>>(count, bsum);
    scan_top    <<<1, 256, 0, stream>>>(bsum, bstart);
    scan_final  <<<SCAN_NB, 256, 0, stream>>>(count, bstart, startp);
    scatter_kernel<<<EB, 256, 0, stream>>>(ei, startp, off, csr_src);

    convert_w_all<<<192, 256, 0, stream>>>(W1l, W1r, W2l, W2r, wsw, wsw2);
    gemm1_mfma <<<N_ / 16, 256, 0, stream>>>(x, wsw, b1l, b1r,
                                             (unsigned short*)xl1b, xr1);
    fused1<<<(N_ * 64 + 255) / 256, 256, 0, stream>>>(csr_src, startp, count,
                                                      xl1b, xr1, att1, bias1, hbuf);

    gemm2_mfma <<<N_ / 16, 256, 0, stream>>>(hbuf, wsw2, b2l, b2r,
                                             (unsigned short*)xl2b, xr2);
    fused2<<<(N_ * 64 + 255) / 256, 256, 0, stream>>>(csr_src, startp, count,
                                                      xl2b, xr2, att2, bias2, out);
}

// Round 18
// 270.036 us; speedup vs baseline: 1.0317x; 1.0215x over previous
//
#include <hip/hip_runtime.h>
#include <hip/hip_bf16.h>

// Problem constants
constexpr int N_  = 50000;
constexpr int E_  = 800000;
constexpr int ET_ = 850000;   // edges + self loops
constexpr float NEG_SLOPE = 0.2f;

constexpr int SCAN_NB = (N_ + 255) / 256;   // 196 scan blocks
constexpr int CSR_CAP = 1250008;            // sum ceil8(count) <= 850K+400K, +8 slack
constexpr int EB      = (ET_ + 255) / 256;  // 3321 edge blocks
constexpr int G1B     = N_ / 16;            // 3125 gemm1 blocks
constexpr int ZERO4   = (50000 + CSR_CAP) / 4;  // 325002 int4 zero slots

typedef __attribute__((ext_vector_type(8))) short short8;   // 8 bf16 = 4 VGPRs
typedef __attribute__((ext_vector_type(4))) float f32x4;    // MFMA accumulator

__device__ inline float leaky(float v) { return fmaxf(v, NEG_SLOPE * v); }

// bf16 round-to-nearest-even (matches __float2bfloat16)
__device__ inline unsigned bf16rn(float f) {
    union { float f; unsigned u; } v; v.f = f;
    return (v.u + 0x7fffu + ((v.u >> 16) & 1u)) >> 16;
}
__device__ inline float2 unpack2(unsigned u) {
    return make_float2(__uint_as_float(u << 16), __uint_as_float(u & 0xffff0000u));
}

// ============ init: zero count+csr_src AND convert W1/W2 fragments ============
// (replaces hipMemsetAsync + convert_w_all: -2 dispatches)
__global__ __launch_bounds__(256) void init_kernel(
        const float* __restrict__ W1l, const float* __restrict__ W1r,
        const float* __restrict__ W2l, const float* __restrict__ W2r,
        unsigned short* __restrict__ wsw, unsigned short* __restrict__ wsw2,
        int4* __restrict__ zbase) {
    int gid = blockIdx.x * 256 + threadIdx.x;
    if (gid < ZERO4) zbase[gid] = make_int4(0, 0, 0, 0);
    if (gid < 32768) {
        int j    = gid & 7;
        int lane = (gid >> 3) & 63;
        int ks   = (gid >> 9) & 3;
        int ct   = gid >> 11;
        int k = ks * 32 + ((lane >> 4) & 3) * 8 + j;
        int c = ct * 16 + (lane & 15);
        float v = (c < 128) ? W1l[k * 128 + c] : W1r[k * 128 + (c - 128)];
        wsw[gid] = (unsigned short)bf16rn(v);
    } else if (gid < 49152) {
        int t2   = gid - 32768;                 // 0..16383
        int j    = t2 & 7;
        int lane = (t2 >> 3) & 63;
        int ks   = (t2 >> 9) & 3;
        int ct   = t2 >> 11;                    // 0..7
        int k = ks * 32 + ((lane >> 4) & 3) * 8 + j;
        int c = ct * 16 + (lane & 15);
        float v = (c < 64) ? W2l[k * 64 + c] : W2r[k * 64 + (c - 64)];
        wsw2[t2] = (unsigned short)bf16rn(v);
    }
}

// ============ hist (blocks < EB)  ||  gemm1_mfma (blocks >= EB) ============
// Independent work overlapped in one dispatch: atomic-heavy hist co-schedules
// with MFMA-heavy gemm1 (separate pipes). -1 dispatch + machine overlap.
__global__ __launch_bounds__(256) void hist_gemm1(
        const int* __restrict__ ei, int* __restrict__ count, int* __restrict__ off,
        const float* __restrict__ x, const unsigned short* __restrict__ wsw,
        const float* __restrict__ bl, const float* __restrict__ br,
        unsigned short* __restrict__ xlu, float* __restrict__ xr1) {
    if (blockIdx.x < EB) {
        int e = blockIdx.x * 256 + threadIdx.x;
        if (e >= ET_) return;
        int d = (e < E_) ? ei[E_ + e] : e - E_;
        off[e] = atomicAdd(&count[d], 1);
        return;
    }
    // ---- gemm1_mfma body (r13/r14-validated) ----
    const int blk  = blockIdx.x - EB;           // 0..G1B-1
    const int wave = threadIdx.x >> 6;
    const int lane = threadIdx.x & 63;
    const int n0 = blk * 16;
    const int m = lane & 15;
    const int q = (lane >> 4) & 3;
    const float* __restrict__ arow = x + (size_t)(n0 + m) * 128 + q * 8;
    short8 afrag[4];
    #pragma unroll
    for (int ks = 0; ks < 4; ++ks) {
        float4 v0 = *(const float4*)(arow + ks * 32);
        float4 v1 = *(const float4*)(arow + ks * 32 + 4);
        short8 a;
        a[0] = (short)bf16rn(v0.x); a[1] = (short)bf16rn(v0.y);
        a[2] = (short)bf16rn(v0.z); a[3] = (short)bf16rn(v0.w);
        a[4] = (short)bf16rn(v1.x); a[5] = (short)bf16rn(v1.y);
        a[6] = (short)bf16rn(v1.z); a[7] = (short)bf16rn(v1.w);
        afrag[ks] = a;
    }
    #pragma unroll
    for (int i = 0; i < 4; ++i) {
        const int ct = wave * 4 + i;
        f32x4 acc = {0.f, 0.f, 0.f, 0.f};
        #pragma unroll
        for (int ks = 0; ks < 4; ++ks) {
            short8 b = *(const short8*)(wsw + ((size_t)(ct * 4 + ks) * 64 + lane) * 8);
            acc = __builtin_amdgcn_mfma_f32_16x16x32_bf16(afrag[ks], b, acc, 0, 0, 0);
        }
        const int col = ct * 16 + m;
        if (ct < 8) {
            float bias = bl[col];
            #pragma unroll
            for (int j = 0; j < 4; ++j) {
                int row = n0 + q * 4 + j;
                xlu[(size_t)row * 128 + col] = (unsigned short)bf16rn(acc[j] + bias);
            }
        } else {
            float bias = br[col - 128];
            #pragma unroll
            for (int j = 0; j < 4; ++j) {
                int row = n0 + q * 4 + j;
                xr1[(size_t)row * 128 + (col - 128)] = acc[j] + bias;
            }
        }
    }
}

// ---- scan over ceil8(count): partial sums, then final (absorbs scan_top) ----
__global__ __launch_bounds__(256) void scan_partial(
        const int* __restrict__ count, int* __restrict__ bsum) {
    __shared__ int red[256];
    int t = threadIdx.x;
    int i = blockIdx.x * 256 + t;
    red[t] = (i < N_) ? ((count[i] + 7) & ~7) : 0;
    __syncthreads();
    #pragma unroll
    for (int o = 128; o > 0; o >>= 1) {
        if (t < o) red[t] += red[t + o];
        __syncthreads();
    }
    if (t == 0) bsum[blockIdx.x] = red[0];
}

// each block redundantly scans the 196 block sums in LDS, then does its
// in-block scan: replaces scan_top + scan_final (-1 dispatch)
__global__ __launch_bounds__(256) void scan_final2(
        const int* __restrict__ count, const int* __restrict__ bsum,
        int* __restrict__ start) {
    __shared__ int top[256];
    __shared__ int buf[256];
    int t = threadIdx.x;
    top[t] = (t < SCAN_NB) ? bsum[t] : 0;
    __syncthreads();
    #pragma unroll
    for (int o = 1; o < 256; o <<= 1) {
        int add = (t >= o) ? top[t - o] : 0;
        __syncthreads();
        top[t] += add;
        __syncthreads();
    }
    int bst = (blockIdx.x == 0) ? 0 : top[blockIdx.x - 1];
    int i = blockIdx.x * 256 + t;
    int v = (i < N_) ? ((count[i] + 7) & ~7) : 0;
    buf[t] = v;
    __syncthreads();
    #pragma unroll
    for (int o = 1; o < 256; o <<= 1) {
        int add = (t >= o) ? buf[t - o] : 0;
        __syncthreads();
        buf[t] += add;
        __syncthreads();
    }
    if (i < N_) start[i] = bst + buf[t] - v;
}

__global__ __launch_bounds__(256) void scatter_kernel(
        const int* __restrict__ ei, const int* __restrict__ start,
        const int* __restrict__ off, int* __restrict__ csr_src) {
    int e = blockIdx.x * 256 + threadIdx.x;
    if (e >= ET_) return;
    int s, d;
    if (e < E_) { s = ei[e]; d = ei[E_ + e]; }
    else        { s = e - E_; d = s; }
    csr_src[start[d] + off[e]] = s;
}

// ====== layer 1 fused attention: ONE wave per node (r15-validated form) ======
__global__ __launch_bounds__(256) void fused1(
        const int* __restrict__ csr_src, const int* __restrict__ start,
        const int* __restrict__ count,
        const unsigned* __restrict__ xl1b, const float* __restrict__ xr1,
        const float* __restrict__ att, const float* __restrict__ bias1,
        float* __restrict__ hout) {
    int t = blockIdx.x * 256 + threadIdx.x;
    int n = __builtin_amdgcn_readfirstlane(t >> 6);   // wave-uniform node id
    int lane = t & 63;
    if (n >= N_) return;
    float2 xr = *(const float2*)(xr1 + (size_t)n * 128 + 2 * lane);
    float2 av = *(const float2*)(att + 2 * lane);
    int p0 = __builtin_amdgcn_readfirstlane(start[n]);
    int p1 = p0 + __builtin_amdgcn_readfirstlane(count[n]);
    float2 acc = make_float2(0.f, 0.f);
    float l = 0.f;
    for (int p = p0; p < p1; p += 4) {
        int4 si = *(const int4*)(csr_src + p);         // uniform, 16B-aligned
        int s0 = __builtin_amdgcn_readfirstlane(si.x);
        int s1 = __builtin_amdgcn_readfirstlane(si.y);
        int s2 = __builtin_amdgcn_readfirstlane(si.z);
        int s3 = __builtin_amdgcn_readfirstlane(si.w);
        float2 x0 = unpack2(xl1b[(size_t)s0 * 64 + lane]);
        float2 x1 = unpack2(xl1b[(size_t)s1 * 64 + lane]);
        float2 x2 = unpack2(xl1b[(size_t)s2 * 64 + lane]);
        float2 x3 = unpack2(xl1b[(size_t)s3 * 64 + lane]);
        float a0 = fmaf(leaky(x0.x + xr.x), av.x, leaky(x0.y + xr.y) * av.y);
        float a1 = fmaf(leaky(x1.x + xr.x), av.x, leaky(x1.y + xr.y) * av.y);
        float a2 = fmaf(leaky(x2.x + xr.x), av.x, leaky(x2.y + xr.y) * av.y);
        float a3 = fmaf(leaky(x3.x + xr.x), av.x, leaky(x3.y + xr.y) * av.y);
        a0 += __shfl_xor(a0, 1); a1 += __shfl_xor(a1, 1);
        a2 += __shfl_xor(a2, 1); a3 += __shfl_xor(a3, 1);
        a0 += __shfl_xor(a0, 2); a1 += __shfl_xor(a1, 2);
        a2 += __shfl_xor(a2, 2); a3 += __shfl_xor(a3, 2);
        a0 += __shfl_xor(a0, 4); a1 += __shfl_xor(a1, 4);
        a2 += __shfl_xor(a2, 4); a3 += __shfl_xor(a3, 4);
        float w0 = __expf(a0);
        float w1 = p + 1 < p1 ? __expf(a1) : 0.f;
        float w2 = p + 2 < p1 ? __expf(a2) : 0.f;
        float w3 = p + 3 < p1 ? __expf(a3) : 0.f;
        acc.x = fmaf(w0, x0.x, acc.x); acc.y = fmaf(w0, x0.y, acc.y); l += w0;
        acc.x = fmaf(w1, x1.x, acc.x); acc.y = fmaf(w1, x1.y, acc.y); l += w1;
        acc.x = fmaf(w2, x2.x, acc.x); acc.y = fmaf(w2, x2.y, acc.y); l += w2;
        acc.x = fmaf(w3, x3.x, acc.x); acc.y = fmaf(w3, x3.y, acc.y); l += w3;
    }
    float2 bv = *(const float2*)(bias1 + 2 * lane);
    float vx = acc.x / l + bv.x;
    float vy = acc.y / l + bv.y;
    float2 o;
    o.x = vx > 0.f ? vx : (__expf(vx) - 1.f);
    o.y = vy > 0.f ? vy : (__expf(vy) - 1.f);
    *(float2*)(hout + (size_t)n * 128 + 2 * lane) = o;
}

// ======================= layer 2 node transforms (MFMA) =======================
__global__ __launch_bounds__(256) void gemm2_mfma(
        const float* __restrict__ hbuf,
        const unsigned short* __restrict__ wsw2,
        const float* __restrict__ bl, const float* __restrict__ br,
        unsigned short* __restrict__ xlu2, float* __restrict__ xr2) {
    const int wave = threadIdx.x >> 6;
    const int lane = threadIdx.x & 63;
    const int n0 = blockIdx.x * 16;
    const int m = lane & 15;
    const int q = (lane >> 4) & 3;
    const float* __restrict__ arow = hbuf + (size_t)(n0 + m) * 128 + q * 8;
    short8 afrag[4];
    #pragma unroll
    for (int ks = 0; ks < 4; ++ks) {
        float4 v0 = *(const float4*)(arow + ks * 32);
        float4 v1 = *(const float4*)(arow + ks * 32 + 4);
        short8 a;
        a[0] = (short)bf16rn(v0.x); a[1] = (short)bf16rn(v0.y);
        a[2] = (short)bf16rn(v0.z); a[3] = (short)bf16rn(v0.w);
        a[4] = (short)bf16rn(v1.x); a[5] = (short)bf16rn(v1.y);
        a[6] = (short)bf16rn(v1.z); a[7] = (short)bf16rn(v1.w);
        afrag[ks] = a;
    }
    #pragma unroll
    for (int i = 0; i < 2; ++i) {
        const int ct = wave * 2 + i;
        f32x4 acc = {0.f, 0.f, 0.f, 0.f};
        #pragma unroll
        for (int ks = 0; ks < 4; ++ks) {
            short8 b = *(const short8*)(wsw2 + ((size_t)(ct * 4 + ks) * 64 + lane) * 8);
            acc = __builtin_amdgcn_mfma_f32_16x16x32_bf16(afrag[ks], b, acc, 0, 0, 0);
        }
        const int col = ct * 16 + m;
        if (ct < 4) {
            float bias = bl[col];
            #pragma unroll
            for (int j = 0; j < 4; ++j) {
                int row = n0 + q * 4 + j;
                xlu2[(size_t)row * 64 + col] = (unsigned short)bf16rn(acc[j] + bias);
            }
        } else {
            float bias = br[col - 64];
            #pragma unroll
            for (int j = 0; j < 4; ++j) {
                int row = n0 + q * 4 + j;
                xr2[(size_t)row * 64 + (col - 64)] = acc[j] + bias;
            }
        }
    }
}

// ====== layer 2 fused attention: one wave per node, TWO edges at a time ======
__global__ __launch_bounds__(256) void fused2(
        const int* __restrict__ csr_src, const int* __restrict__ start,
        const int* __restrict__ count,
        const unsigned* __restrict__ xl2b, const float* __restrict__ xr2,
        const float* __restrict__ att, const float* __restrict__ bias2,
        float* __restrict__ out) {
    int t = blockIdx.x * 256 + threadIdx.x;
    int n = __builtin_amdgcn_readfirstlane(t >> 6);   // wave-uniform node id
    int lane = t & 63;
    int half = lane >> 5;                 // which edge of the pair
    int lc   = lane & 31;                 // channel pair id
    if (n >= N_) return;
    float2 xr = *(const float2*)(xr2 + (size_t)n * 64 + 2 * lc);
    float2 av = *(const float2*)(att + 2 * lc);
    int p0 = __builtin_amdgcn_readfirstlane(start[n]);
    int p1 = p0 + __builtin_amdgcn_readfirstlane(count[n]);
    float2 acc = make_float2(0.f, 0.f);
    float l = 0.f;
    for (int p = p0; p < p1; p += 8) {
        int4 ia = *(const int4*)(csr_src + p);         // uniform, aligned
        int4 ib = *(const int4*)(csr_src + p + 4);
        int sx[8];
        sx[0] = __builtin_amdgcn_readfirstlane(ia.x);
        sx[1] = __builtin_amdgcn_readfirstlane(ia.y);
        sx[2] = __builtin_amdgcn_readfirstlane(ia.z);
        sx[3] = __builtin_amdgcn_readfirstlane(ia.w);
        sx[4] = __builtin_amdgcn_readfirstlane(ib.x);
        sx[5] = __builtin_amdgcn_readfirstlane(ib.y);
        sx[6] = __builtin_amdgcn_readfirstlane(ib.z);
        sx[7] = __builtin_amdgcn_readfirstlane(ib.w);
        #pragma unroll
        for (int u = 0; u < 4; ++u) {
            int pe = p + 2 * u + half;
            int s  = sx[2 * u + half];
            float2 xv = unpack2(xl2b[(size_t)s * 32 + lc]);
            float a = fmaf(leaky(xv.x + xr.x), av.x, leaky(xv.y + xr.y) * av.y);
            a += __shfl_xor(a, 1);
            a += __shfl_xor(a, 2);
            a += __shfl_xor(a, 4);
            a += __shfl_xor(a, 8);
            a += __shfl_xor(a, 16);
            float w = pe < p1 ? __expf(a) : 0.f;
            acc.x = fmaf(w, xv.x, acc.x);
            acc.y = fmaf(w, xv.y, acc.y);
            l += w;
        }
    }
    acc.x += __shfl_xor(acc.x, 32);
    acc.y += __shfl_xor(acc.y, 32);
    l     += __shfl_xor(l, 32);
    if (half == 0) {
        float2 bv = *(const float2*)(bias2 + 2 * lc);
        float2 o;
        o.x = acc.x / l + bv.x;
        o.y = acc.y / l + bv.y;
        *(float2*)(out + (size_t)n * 64 + 2 * lc) = o;
    }
}

extern "C" void kernel_launch(void* const* d_in, const int* in_sizes, int n_in,
                              void* d_out, int out_size, void* d_ws, size_t ws_size,
                              hipStream_t stream) {
    (void)in_sizes; (void)n_in; (void)out_size; (void)ws_size;
    const float* x     = (const float*)d_in[0];
    const int*   ei    = (const int*)d_in[1];
    const float* W1l   = (const float*)d_in[2];
    const float* b1l   = (const float*)d_in[3];
    const float* W1r   = (const float*)d_in[4];
    const float* b1r   = (const float*)d_in[5];
    const float* att1  = (const float*)d_in[6];
    const float* bias1 = (const float*)d_in[7];
    const float* W2l   = (const float*)d_in[8];
    const float* b2l   = (const float*)d_in[9];
    const float* W2r   = (const float*)d_in[10];
    const float* b2r   = (const float*)d_in[11];
    const float* att2  = (const float*)d_in[12];
    const float* bias2 = (const float*)d_in[13];
    float* out = (float*)d_out;

    // workspace layout (r15-identical). count+csr_src contiguous, zeroed by
    // init_kernel every call (csr pad slots must be 0 — replay re-poisons ws).
    float* xr1      = (float*)d_ws;                // 6,400,000 f
    float* hbuf     = xr1 + 6400000;               // 6,400,000 f
    unsigned* xl1b  = (unsigned*)(hbuf + 6400000); // 3,200,000 u (bf16 pairs)
    int* count   = (int*)(xl1b + 3200000);         //    50,000 i
    int* csr_src = count + 50000;                  // 1,250,008 i (8-aligned segs)
    int* startp  = csr_src + CSR_CAP;              //    50,000 i
    int* off     = startp + 50000;                 //   850,000 i
    int* bsum    = off + 850000;                   //       256 i
    int* bstart  = bsum + 256;                     //       256 i (unused now)
    unsigned short* wsw2 = (unsigned short*)(bstart + 256);  // 16,384 bf16 (32 KB)
    unsigned* xl2b = xl1b;                         // alias: xl1b dead after fused1
    float* xr2     = xr1;                          // alias: xr1 dead after fused1
    unsigned short* wsw = (unsigned short*)hbuf;   // 64 KB W1 frags in hbuf front

    init_kernel<<<(ZERO4 + 255) / 256, 256, 0, stream>>>(W1l, W1r, W2l, W2r,
                                                         wsw, wsw2, (int4*)count);
    hist_gemm1 <<<EB + G1B, 256, 0, stream>>>(ei, count, off, x, wsw, b1l, b1r,
                                              (unsigned short*)xl1b, xr1);
    scan_partial<<<SCAN_NB, 256, 0, stream>>>(count, bsum);
    scan_final2 <<<SCAN_NB, 256, 0, stream>>>(count, bsum, startp);
    scatter_kernel<<<EB, 256, 0, stream>>>(ei, startp, off, csr_src);

    fused1<<<(N_ * 64 + 255) / 256, 256, 0, stream>>>(csr_src, startp, count,
                                                      xl1b, xr1, att1, bias1, hbuf);
    gemm2_mfma <<<N_ / 16, 256, 0, stream>>>(hbuf, wsw2, b2l, b2r,
                                             (unsigned short*)xl2b, xr2);
    fused2<<<(N_ * 64 + 255) / 256, 256, 0, stream>>>(csr_src, startp, count,
                                                      xl2b, xr2, att2, bias2, out);
}

// Round 19
// 269.163 us; speedup vs baseline: 1.0350x; 1.0032x over previous
//
#include <hip/hip_runtime.h>
#include <hip/hip_bf16.h>

// Problem constants
constexpr int N_  = 50000;
constexpr int E_  = 800000;
constexpr int ET_ = 850000;   // edges + self loops
constexpr float NEG_SLOPE = 0.2f;

constexpr int SCAN_NB = (N_ + 255) / 256;   // 196 scan blocks
constexpr int CSR_CAP = 1250008;            // sum ceil8(count) <= 850K+400K, +8 slack
constexpr int HT      = ET_ / 8;            // 106,250 hist threads (8 edges each)
constexpr int HB      = (HT + 255) / 256;   // 416 hist blocks
constexpr int G1B     = N_ / 16;            // 3125 gemm1 blocks
constexpr int ZERO4   = (50000 + CSR_CAP) / 4;  // 325002 int4 zero slots

typedef __attribute__((ext_vector_type(8))) short short8;   // 8 bf16 = 4 VGPRs
typedef __attribute__((ext_vector_type(4))) float f32x4;    // MFMA accumulator

__device__ inline float leaky(float v) { return fmaxf(v, NEG_SLOPE * v); }

// bf16 round-to-nearest-even (matches __float2bfloat16)
__device__ inline unsigned bf16rn(float f) {
    union { float f; unsigned u; } v; v.f = f;
    return (v.u + 0x7fffu + ((v.u >> 16) & 1u)) >> 16;
}
__device__ inline float2 unpack2(unsigned u) {
    return make_float2(__uint_as_float(u << 16), __uint_as_float(u & 0xffff0000u));
}

// dst of edge e (self loops at e >= E_)
__device__ inline int edge_dst(int e, const int* __restrict__ ei) {
    return (e < E_) ? ei[E_ + e] : e - E_;
}
__device__ inline int edge_src(int e, const int* __restrict__ ei) {
    return (e < E_) ? ei[e] : e - E_;
}

// ============ init: zero count+csr_src AND convert W1/W2 fragments ============
__global__ __launch_bounds__(256) void init_kernel(
        const float* __restrict__ W1l, const float* __restrict__ W1r,
        const float* __restrict__ W2l, const float* __restrict__ W2r,
        unsigned short* __restrict__ wsw, unsigned short* __restrict__ wsw2,
        int4* __restrict__ zbase) {
    int gid = blockIdx.x * 256 + threadIdx.x;
    if (gid < ZERO4) zbase[gid] = make_int4(0, 0, 0, 0);
    if (gid < 32768) {
        int j    = gid & 7;
        int lane = (gid >> 3) & 63;
        int ks   = (gid >> 9) & 3;
        int ct   = gid >> 11;
        int k = ks * 32 + ((lane >> 4) & 3) * 8 + j;
        int c = ct * 16 + (lane & 15);
        float v = (c < 128) ? W1l[k * 128 + c] : W1r[k * 128 + (c - 128)];
        wsw[gid] = (unsigned short)bf16rn(v);
    } else if (gid < 49152) {
        int t2   = gid - 32768;                 // 0..16383
        int j    = t2 & 7;
        int lane = (t2 >> 3) & 63;
        int ks   = (t2 >> 9) & 3;
        int ct   = t2 >> 11;                    // 0..7
        int k = ks * 32 + ((lane >> 4) & 3) * 8 + j;
        int c = ct * 16 + (lane & 15);
        float v = (c < 64) ? W2l[k * 64 + c] : W2r[k * 64 + (c - 64)];
        wsw2[t2] = (unsigned short)bf16rn(v);
    }
}

// ============ hist (8 edges/thread, blocks < HB)  ||  gemm1_mfma ============
// hist: 8 INDEPENDENT atomic-with-return ops in flight per thread (r18's
// 1/thread was pure latency, VALUBusy 6.6%). gemm1 blocks fill the machine
// while hist waves wait on atomic round-trips.
__global__ __launch_bounds__(256) void hist_gemm1(
        const int* __restrict__ ei, int* __restrict__ count, int* __restrict__ off,
        const float* __restrict__ x, const unsigned short* __restrict__ wsw,
        const float* __restrict__ bl, const float* __restrict__ br,
        unsigned short* __restrict__ xlu, float* __restrict__ xr1) {
    if (blockIdx.x < HB) {
        int t = blockIdx.x * 256 + threadIdx.x;
        if (t >= HT) return;
        int e8 = t * 8;
        int d[8], o[8];
        #pragma unroll
        for (int i = 0; i < 8; ++i) d[i] = edge_dst(e8 + i, ei);
        #pragma unroll
        for (int i = 0; i < 8; ++i) o[i] = atomicAdd(&count[d[i]], 1);
        int4* op = (int4*)(off + e8);
        op[0] = make_int4(o[0], o[1], o[2], o[3]);
        op[1] = make_int4(o[4], o[5], o[6], o[7]);
        return;
    }
    // ---- gemm1_mfma body (r13/r14-validated) ----
    const int blk  = blockIdx.x - HB;           // 0..G1B-1
    const int wave = threadIdx.x >> 6;
    const int lane = threadIdx.x & 63;
    const int n0 = blk * 16;
    const int m = lane & 15;
    const int q = (lane >> 4) & 3;
    const float* __restrict__ arow = x + (size_t)(n0 + m) * 128 + q * 8;
    short8 afrag[4];
    #pragma unroll
    for (int ks = 0; ks < 4; ++ks) {
        float4 v0 = *(const float4*)(arow + ks * 32);
        float4 v1 = *(const float4*)(arow + ks * 32 + 4);
        short8 a;
        a[0] = (short)bf16rn(v0.x); a[1] = (short)bf16rn(v0.y);
        a[2] = (short)bf16rn(v0.z); a[3] = (short)bf16rn(v0.w);
        a[4] = (short)bf16rn(v1.x); a[5] = (short)bf16rn(v1.y);
        a[6] = (short)bf16rn(v1.z); a[7] = (short)bf16rn(v1.w);
        afrag[ks] = a;
    }
    #pragma unroll
    for (int i = 0; i < 4; ++i) {
        const int ct = wave * 4 + i;
        f32x4 acc = {0.f, 0.f, 0.f, 0.f};
        #pragma unroll
        for (int ks = 0; ks < 4; ++ks) {
            short8 b = *(const short8*)(wsw + ((size_t)(ct * 4 + ks) * 64 + lane) * 8);
            acc = __builtin_amdgcn_mfma_f32_16x16x32_bf16(afrag[ks], b, acc, 0, 0, 0);
        }
        const int col = ct * 16 + m;
        if (ct < 8) {
            float bias = bl[col];
            #pragma unroll
            for (int j = 0; j < 4; ++j) {
                int row = n0 + q * 4 + j;
                xlu[(size_t)row * 128 + col] = (unsigned short)bf16rn(acc[j] + bias);
            }
        } else {
            float bias = br[col - 128];
            #pragma unroll
            for (int j = 0; j < 4; ++j) {
                int row = n0 + q * 4 + j;
                xr1[(size_t)row * 128 + (col - 128)] = acc[j] + bias;
            }
        }
    }
}

// ---- scan over ceil8(count): partial sums, then final (absorbs scan_top) ----
__global__ __launch_bounds__(256) void scan_partial(
        const int* __restrict__ count, int* __restrict__ bsum) {
    __shared__ int red[256];
    int t = threadIdx.x;
    int i = blockIdx.x * 256 + t;
    red[t] = (i < N_) ? ((count[i] + 7) & ~7) : 0;
    __syncthreads();
    #pragma unroll
    for (int o = 128; o > 0; o >>= 1) {
        if (t < o) red[t] += red[t + o];
        __syncthreads();
    }
    if (t == 0) bsum[blockIdx.x] = red[0];
}

__global__ __launch_bounds__(256) void scan_final2(
        const int* __restrict__ count, const int* __restrict__ bsum,
        int* __restrict__ start) {
    __shared__ int top[256];
    __shared__ int buf[256];
    int t = threadIdx.x;
    top[t] = (t < SCAN_NB) ? bsum[t] : 0;
    __syncthreads();
    #pragma unroll
    for (int o = 1; o < 256; o <<= 1) {
        int add = (t >= o) ? top[t - o] : 0;
        __syncthreads();
        top[t] += add;
        __syncthreads();
    }
    int bst = (blockIdx.x == 0) ? 0 : top[blockIdx.x - 1];
    int i = blockIdx.x * 256 + t;
    int v = (i < N_) ? ((count[i] + 7) & ~7) : 0;
    buf[t] = v;
    __syncthreads();
    #pragma unroll
    for (int o = 1; o < 256; o <<= 1) {
        int add = (t >= o) ? buf[t - o] : 0;
        __syncthreads();
        buf[t] += add;
        __syncthreads();
    }
    if (i < N_) start[i] = bst + buf[t] - v;
}

// ---- scatter: 8 edges/thread for memory-level parallelism ----
__global__ __launch_bounds__(256) void scatter_kernel(
        const int* __restrict__ ei, const int* __restrict__ start,
        const int* __restrict__ off, int* __restrict__ csr_src) {
    int t = blockIdx.x * 256 + threadIdx.x;
    if (t >= HT) return;
    int e8 = t * 8;
    int4 o0 = *(const int4*)(off + e8);
    int4 o1 = *(const int4*)(off + e8 + 4);
    int o[8] = {o0.x, o0.y, o0.z, o0.w, o1.x, o1.y, o1.z, o1.w};
    int s[8], d[8];
    #pragma unroll
    for (int i = 0; i < 8; ++i) {
        s[i] = edge_src(e8 + i, ei);
        d[i] = edge_dst(e8 + i, ei);
    }
    int st[8];
    #pragma unroll
    for (int i = 0; i < 8; ++i) st[i] = start[d[i]];
    #pragma unroll
    for (int i = 0; i < 8; ++i) csr_src[st[i] + o[i]] = s[i];
}

// ====== layer 1 fused attention: ONE wave per node (r15-validated form) ======
__global__ __launch_bounds__(256) void fused1(
        const int* __restrict__ csr_src, const int* __restrict__ start,
        const int* __restrict__ count,
        const unsigned* __restrict__ xl1b, const float* __restrict__ xr1,
        const float* __restrict__ att, const float* __restrict__ bias1,
        float* __restrict__ hout) {
    int t = blockIdx.x * 256 + threadIdx.x;
    int n = __builtin_amdgcn_readfirstlane(t >> 6);   // wave-uniform node id
    int lane = t & 63;
    if (n >= N_) return;
    float2 xr = *(const float2*)(xr1 + (size_t)n * 128 + 2 * lane);
    float2 av = *(const float2*)(att + 2 * lane);
    int p0 = __builtin_amdgcn_readfirstlane(start[n]);
    int p1 = p0 + __builtin_amdgcn_readfirstlane(count[n]);
    float2 acc = make_float2(0.f, 0.f);
    float l = 0.f;
    for (int p = p0; p < p1; p += 4) {
        int4 si = *(const int4*)(csr_src + p);         // uniform, 16B-aligned
        int s0 = __builtin_amdgcn_readfirstlane(si.x);
        int s1 = __builtin_amdgcn_readfirstlane(si.y);
        int s2 = __builtin_amdgcn_readfirstlane(si.z);
        int s3 = __builtin_amdgcn_readfirstlane(si.w);
        float2 x0 = unpack2(xl1b[(size_t)s0 * 64 + lane]);
        float2 x1 = unpack2(xl1b[(size_t)s1 * 64 + lane]);
        float2 x2 = unpack2(xl1b[(size_t)s2 * 64 + lane]);
        float2 x3 = unpack2(xl1b[(size_t)s3 * 64 + lane]);
        float a0 = fmaf(leaky(x0.x + xr.x), av.x, leaky(x0.y + xr.y) * av.y);
        float a1 = fmaf(leaky(x1.x + xr.x), av.x, leaky(x1.y + xr.y) * av.y);
        float a2 = fmaf(leaky(x2.x + xr.x), av.x, leaky(x2.y + xr.y) * av.y);
        float a3 = fmaf(leaky(x3.x + xr.x), av.x, leaky(x3.y + xr.y) * av.y);
        a0 += __shfl_xor(a0, 1); a1 += __shfl_xor(a1, 1);
        a2 += __shfl_xor(a2, 1); a3 += __shfl_xor(a3, 1);
        a0 += __shfl_xor(a0, 2); a1 += __shfl_xor(a1, 2);
        a2 += __shfl_xor(a2, 2); a3 += __shfl_xor(a3, 2);
        a0 += __shfl_xor(a0, 4); a1 += __shfl_xor(a1, 4);
        a2 += __shfl_xor(a2, 4); a3 += __shfl_xor(a3, 4);
        float w0 = __expf(a0);
        float w1 = p + 1 < p1 ? __expf(a1) : 0.f;
        float w2 = p + 2 < p1 ? __expf(a2) : 0.f;
        float w3 = p + 3 < p1 ? __expf(a3) : 0.f;
        acc.x = fmaf(w0, x0.x, acc.x); acc.y = fmaf(w0, x0.y, acc.y); l += w0;
        acc.x = fmaf(w1, x1.x, acc.x); acc.y = fmaf(w1, x1.y, acc.y); l += w1;
        acc.x = fmaf(w2, x2.x, acc.x); acc.y = fmaf(w2, x2.y, acc.y); l += w2;
        acc.x = fmaf(w3, x3.x, acc.x); acc.y = fmaf(w3, x3.y, acc.y); l += w3;
    }
    float2 bv = *(const float2*)(bias1 + 2 * lane);
    float vx = acc.x / l + bv.x;
    float vy = acc.y / l + bv.y;
    float2 o;
    o.x = vx > 0.f ? vx : (__expf(vx) - 1.f);
    o.y = vy > 0.f ? vy : (__expf(vy) - 1.f);
    *(float2*)(hout + (size_t)n * 128 + 2 * lane) = o;
}

// ======================= layer 2 node transforms (MFMA) =======================
__global__ __launch_bounds__(256) void gemm2_mfma(
        const float* __restrict__ hbuf,
        const unsigned short* __restrict__ wsw2,
        const float* __restrict__ bl, const float* __restrict__ br,
        unsigned short* __restrict__ xlu2, float* __restrict__ xr2) {
    const int wave = threadIdx.x >> 6;
    const int lane = threadIdx.x & 63;
    const int n0 = blockIdx.x * 16;
    const int m = lane & 15;
    const int q = (lane >> 4) & 3;
    const float* __restrict__ arow = hbuf + (size_t)(n0 + m) * 128 + q * 8;
    short8 afrag[4];
    #pragma unroll
    for (int ks = 0; ks < 4; ++ks) {
        float4 v0 = *(const float4*)(arow + ks * 32);
        float4 v1 = *(const float4*)(arow + ks * 32 + 4);
        short8 a;
        a[0] = (short)bf16rn(v0.x); a[1] = (short)bf16rn(v0.y);
        a[2] = (short)bf16rn(v0.z); a[3] = (short)bf16rn(v0.w);
        a[4] = (short)bf16rn(v1.x); a[5] = (short)bf16rn(v1.y);
        a[6] = (short)bf16rn(v1.z); a[7] = (short)bf16rn(v1.w);
        afrag[ks] = a;
    }
    #pragma unroll
    for (int i = 0; i < 2; ++i) {
        const int ct = wave * 2 + i;
        f32x4 acc = {0.f, 0.f, 0.f, 0.f};
        #pragma unroll
        for (int ks = 0; ks < 4; ++ks) {
            short8 b = *(const short8*)(wsw2 + ((size_t)(ct * 4 + ks) * 64 + lane) * 8);
            acc = __builtin_amdgcn_mfma_f32_16x16x32_bf16(afrag[ks], b, acc, 0, 0, 0);
        }
        const int col = ct * 16 + m;
        if (ct < 4) {
            float bias = bl[col];
            #pragma unroll
            for (int j = 0; j < 4; ++j) {
                int row = n0 + q * 4 + j;
                xlu2[(size_t)row * 64 + col] = (unsigned short)bf16rn(acc[j] + bias);
            }
        } else {
            float bias = br[col - 64];
            #pragma unroll
            for (int j = 0; j < 4; ++j) {
                int row = n0 + q * 4 + j;
                xr2[(size_t)row * 64 + (col - 64)] = acc[j] + bias;
            }
        }
    }
}

// ====== layer 2 fused attention: one wave per node, TWO edges at a time ======
__global__ __launch_bounds__(256) void fused2(
        const int* __restrict__ csr_src, const int* __restrict__ start,
        const int* __restrict__ count,
        const unsigned* __restrict__ xl2b, const float* __restrict__ xr2,
        const float* __restrict__ att, const float* __restrict__ bias2,
        float* __restrict__ out) {
    int t = blockIdx.x * 256 + threadIdx.x;
    int n = __builtin_amdgcn_readfirstlane(t >> 6);   // wave-uniform node id
    int lane = t & 63;
    int half = lane >> 5;                 // which edge of the pair
    int lc   = lane & 31;                 // channel pair id
    if (n >= N_) return;
    float2 xr = *(const float2*)(xr2 + (size_t)n * 64 + 2 * lc);
    float2 av = *(const float2*)(att + 2 * lc);
    int p0 = __builtin_amdgcn_readfirstlane(start[n]);
    int p1 = p0 + __builtin_amdgcn_readfirstlane(count[n]);
    float2 acc = make_float2(0.f, 0.f);
    float l = 0.f;
    for (int p = p0; p < p1; p += 8) {
        int4 ia = *(const int4*)(csr_src + p);         // uniform, aligned
        int4 ib = *(const int4*)(csr_src + p + 4);
        int sx[8];
        sx[0] = __builtin_amdgcn_readfirstlane(ia.x);
        sx[1] = __builtin_amdgcn_readfirstlane(ia.y);
        sx[2] = __builtin_amdgcn_readfirstlane(ia.z);
        sx[3] = __builtin_amdgcn_readfirstlane(ia.w);
        sx[4] = __builtin_amdgcn_readfirstlane(ib.x);
        sx[5] = __builtin_amdgcn_readfirstlane(ib.y);
        sx[6] = __builtin_amdgcn_readfirstlane(ib.z);
        sx[7] = __builtin_amdgcn_readfirstlane(ib.w);
        #pragma unroll
        for (int u = 0; u < 4; ++u) {
            int pe = p + 2 * u + half;
            int s  = sx[2 * u + half];
            float2 xv = unpack2(xl2b[(size_t)s * 32 + lc]);
            float a = fmaf(leaky(xv.x + xr.x), av.x, leaky(xv.y + xr.y) * av.y);
            a += __shfl_xor(a, 1);
            a += __shfl_xor(a, 2);
            a += __shfl_xor(a, 4);
            a += __shfl_xor(a, 8);
            a += __shfl_xor(a, 16);
            float w = pe < p1 ? __expf(a) : 0.f;
            acc.x = fmaf(w, xv.x, acc.x);
            acc.y = fmaf(w, xv.y, acc.y);
            l += w;
        }
    }
    acc.x += __shfl_xor(acc.x, 32);
    acc.y += __shfl_xor(acc.y, 32);
    l     += __shfl_xor(l, 32);
    if (half == 0) {
        float2 bv = *(const float2*)(bias2 + 2 * lc);
        float2 o;
        o.x = acc.x / l + bv.x;
        o.y = acc.y / l + bv.y;
        *(float2*)(out + (size_t)n * 64 + 2 * lc) = o;
    }
}

extern "C" void kernel_launch(void* const* d_in, const int* in_sizes, int n_in,
                              void* d_out, int out_size, void* d_ws, size_t ws_size,
                              hipStream_t stream) {
    (void)in_sizes; (void)n_in; (void)out_size; (void)ws_size;
    const float* x     = (const float*)d_in[0];
    const int*   ei    = (const int*)d_in[1];
    const float* W1l   = (const float*)d_in[2];
    const float* b1l   = (const float*)d_in[3];
    const float* W1r   = (const float*)d_in[4];
    const float* b1r   = (const float*)d_in[5];
    const float* att1  = (const float*)d_in[6];
    const float* bias1 = (const float*)d_in[7];
    const float* W2l   = (const float*)d_in[8];
    const float* b2l   = (const float*)d_in[9];
    const float* W2r   = (const float*)d_in[10];
    const float* b2r   = (const float*)d_in[11];
    const float* att2  = (const float*)d_in[12];
    const float* bias2 = (const float*)d_in[13];
    float* out = (float*)d_out;

    // workspace layout (r15-identical). count+csr_src contiguous, zeroed by
    // init_kernel every call (csr pad slots must be 0 — replay re-poisons ws).
    float* xr1      = (float*)d_ws;                // 6,400,000 f
    float* hbuf     = xr1 + 6400000;               // 6,400,000 f
    unsigned* xl1b  = (unsigned*)(hbuf + 6400000); // 3,200,000 u (bf16 pairs)
    int* count   = (int*)(xl1b + 3200000);         //    50,000 i
    int* csr_src = count + 50000;                  // 1,250,008 i (8-aligned segs)
    int* startp  = csr_src + CSR_CAP;              //    50,000 i
    int* off     = startp + 50000;                 //   850,000 i
    int* bsum    = off + 850000;                   //       256 i
    int* bstart  = bsum + 256;                     //       256 i (unused now)
    unsigned short* wsw2 = (unsigned short*)(bstart + 256);  // 16,384 bf16 (32 KB)
    unsigned* xl2b = xl1b;                         // alias: xl1b dead after fused1
    float* xr2     = xr1;                          // alias: xr1 dead after fused1
    unsigned short* wsw = (unsigned short*)hbuf;   // 64 KB W1 frags in hbuf front

    init_kernel<<<(ZERO4 + 255) / 256, 256, 0, stream>>>(W1l, W1r, W2l, W2r,
                                                         wsw, wsw2, (int4*)count);
    hist_gemm1 <<<HB + G1B, 256, 0, stream>>>(ei, count, off, x, wsw, b1l, b1r,
                                              (unsigned short*)xl1b, xr1);
    scan_partial<<<SCAN_NB, 256, 0, stream>>>(count, bsum);
    scan_final2 <<<SCAN_NB, 256, 0, stream>>>(count, bsum, startp);
    scatter_kernel<<<(HT + 255) / 256, 256, 0, stream>>>(ei, startp, off, csr_src);

    fused1<<<(N_ * 64 + 255) / 256, 256, 0, stream>>>(csr_src, startp, count,
                                                      xl1b, xr1, att1, bias1, hbuf);
    gemm2_mfma <<<N_ / 16, 256, 0, stream>>>(hbuf, wsw2, b2l, b2r,
                                             (unsigned short*)xl2b, xr2);
    fused2<<<(N_ * 64 + 255) / 256, 256, 0, stream>>>(csr_src, startp, count,
                                                      xl2b, xr2, att2, bias2, out);
}